// Round 1
// baseline (203.183 us; speedup 1.0000x reference)
//
#include <hip/hip_runtime.h>

// MultiHeadGraphAttention: B=8, N=1024, IN=OUT=256, H=8, d_k=32
// Pipeline: prep(cvt) -> QKV gemm (bf16 MFMA) -> fused masked attention -> out proj.

typedef __bf16 bf16x8 __attribute__((ext_vector_type(8)));
typedef float f32x4 __attribute__((ext_vector_type(4)));

#define DEV static __device__ __forceinline__

DEV unsigned short f2bf(float f) {   // RNE f32 -> bf16 bits
  union { float f; unsigned u; } x; x.f = f;
  unsigned r = x.u + 0x7fffu + ((x.u >> 16) & 1u);
  return (unsigned short)(r >> 16);
}

DEV f32x4 mfma16(bf16x8 a, bf16x8 b, f32x4 c) {
  return __builtin_amdgcn_mfma_f32_16x16x32_bf16(a, b, c, 0, 0, 0);
}

DEV bf16x8 ldfrag(const unsigned short* p) {
  return *reinterpret_cast<const bf16x8*>(p);
}

// ---------------- prep: X f32->bf16 ; W_{q,k,v,o} -> bf16 transposed [n][k] ----
__global__ __launch_bounds__(256) void k_prep(
    const float* __restrict__ X,
    const float* __restrict__ Wq, const float* __restrict__ Wk,
    const float* __restrict__ Wv, const float* __restrict__ Wo,
    unsigned short* __restrict__ Xbf, unsigned short* __restrict__ Wt) {
  const int tid = blockIdx.x * 256 + threadIdx.x;
  const int NX4 = (8192 * 256) / 4;           // 524288 float4s of X
  if (tid < NX4) {
    float4 v = reinterpret_cast<const float4*>(X)[tid];
    ushort4 o;
    o.x = f2bf(v.x); o.y = f2bf(v.y); o.z = f2bf(v.z); o.w = f2bf(v.w);
    reinterpret_cast<ushort4*>(Xbf)[tid] = o;
  } else {
    int t = tid - NX4;                        // 0 .. 262143
    int mat = t >> 16;
    int e = t & 65535;
    int n = e >> 8, k = e & 255;              // output Wt[mat][n][k]
    const float* W = (mat == 0) ? Wq : (mat == 1) ? Wk : (mat == 2) ? Wv : Wo;
    Wt[t] = f2bf(W[k * 256 + n]);
  }
}

// ---------------- QKV projection GEMM -----------------------------------------
// grid 256 (m-tiles of 32), block 256 (4 waves). Wave w covers 16 cols of each
// 64-col slab. Outputs: Q,K as [B,H,N,32] bf16; V transposed as [B,H,32,N] bf16.
__global__ __launch_bounds__(256) void k_qkv(
    const unsigned short* __restrict__ Xbf, const unsigned short* __restrict__ Wt,
    const float* __restrict__ bq, const float* __restrict__ bk,
    const float* __restrict__ bv,
    unsigned short* __restrict__ Qb, unsigned short* __restrict__ Kb,
    unsigned short* __restrict__ Vt) {
  const int lane = threadIdx.x & 63;
  const int w = threadIdx.x >> 6;
  const int lr = lane & 15, lg = lane >> 4;
  const int m0 = blockIdx.x << 5;

  bf16x8 a[2][8];
  #pragma unroll
  for (int mi = 0; mi < 2; ++mi)
    #pragma unroll
    for (int ks = 0; ks < 8; ++ks)
      a[mi][ks] = ldfrag(Xbf + (m0 + mi * 16 + lr) * 256 + ks * 32 + lg * 8);

  for (int nb = 0; nb < 12; ++nb) {
    const int c0 = nb * 64 + w * 16;          // global col in [0,768)
    const int mat = c0 >> 8;                  // 0=Q 1=K 2=V
    const int nloc = c0 & 255;
    const unsigned short* Wm = Wt + mat * 65536;
    bf16x8 bfr[8];
    #pragma unroll
    for (int ks = 0; ks < 8; ++ks)
      bfr[ks] = ldfrag(Wm + (nloc + lr) * 256 + ks * 32 + lg * 8);
    f32x4 acc0 = {0.f, 0.f, 0.f, 0.f}, acc1 = {0.f, 0.f, 0.f, 0.f};
    #pragma unroll
    for (int ks = 0; ks < 8; ++ks) {
      acc0 = mfma16(a[0][ks], bfr[ks], acc0);
      acc1 = mfma16(a[1][ks], bfr[ks], acc1);
    }
    const float* bias = (mat == 0) ? bq : (mat == 1) ? bk : bv;
    const float bb = bias[nloc + lr];
    const int cm = nloc + lr;                 // col within the 256-wide matrix
    const int hh = cm >> 5, d = cm & 31;
    #pragma unroll
    for (int mi = 0; mi < 2; ++mi) {
      f32x4 acc = mi ? acc1 : acc0;
      #pragma unroll
      for (int i = 0; i < 4; ++i) {
        const int row = m0 + mi * 16 + lg * 4 + i;
        const int bidx = row >> 10, nn = row & 1023;
        const unsigned short val = f2bf(acc[i] + bb);
        if (mat == 0)
          Qb[(((bidx * 8 + hh) * 1024) + nn) * 32 + d] = val;
        else if (mat == 1)
          Kb[(((bidx * 8 + hh) * 1024) + nn) * 32 + d] = val;
        else
          Vt[(((bidx * 8 + hh) * 32) + d) * 1024 + nn] = val;
      }
    }
  }
}

// ---------------- fused masked attention --------------------------------------
// grid = B * N/32 = 256 blocks, block = 512 threads = 8 waves, wave = head.
// Flash-style online softmax; A/D read straight from global (all 8 waves of a
// block hit the same lines -> L1). P transposed via per-wave LDS buffer.
__global__ __launch_bounds__(512) void k_attn(
    const unsigned short* __restrict__ Qb, const unsigned short* __restrict__ Kb,
    const unsigned short* __restrict__ Vt, const int* __restrict__ A,
    const float* __restrict__ D, const float* __restrict__ dscale,
    unsigned short* __restrict__ AO) {
  __shared__ unsigned short P[8][32][40];
  const int lane = threadIdx.x & 63;
  const int h = threadIdx.x >> 6;
  const int lr = lane & 15, lg = lane >> 4;
  const int b = blockIdx.x >> 5;
  const int q0 = (blockIdx.x & 31) << 5;
  const float ds = dscale[0];
  const float scale = 0.17677669529663689f;   // 1/sqrt(32)

  const unsigned short* Qh = Qb + (size_t)((b * 8 + h) * 1024) * 32;
  const unsigned short* Kh = Kb + (size_t)((b * 8 + h) * 1024) * 32;
  const unsigned short* Vh = Vt + (size_t)((b * 8 + h) * 32) * 1024;
  const float* Db = D + ((size_t)b << 20);
  const int* Ab = A + ((size_t)b << 20);

  bf16x8 qf[2];
  qf[0] = ldfrag(Qh + (q0 + lr) * 32 + lg * 8);
  qf[1] = ldfrag(Qh + (q0 + 16 + lr) * 32 + lg * 8);

  f32x4 o[2][2];
  float m[2][4], l[2][4];
  #pragma unroll
  for (int qi = 0; qi < 2; ++qi) {
    #pragma unroll
    for (int i = 0; i < 4; ++i) { m[qi][i] = -1e30f; l[qi][i] = 0.f; }
    #pragma unroll
    for (int di = 0; di < 2; ++di) o[qi][di] = f32x4{0.f, 0.f, 0.f, 0.f};
  }

  for (int kt = 0; kt < 32; ++kt) {
    const int k0 = kt << 5;
    bf16x8 kf[2], vf[2];
    kf[0] = ldfrag(Kh + (k0 + lr) * 32 + lg * 8);
    kf[1] = ldfrag(Kh + (k0 + 16 + lr) * 32 + lg * 8);
    vf[0] = ldfrag(Vh + lr * 1024 + k0 + lg * 8);
    vf[1] = ldfrag(Vh + (16 + lr) * 1024 + k0 + lg * 8);

    const f32x4 zz = {0.f, 0.f, 0.f, 0.f};
    f32x4 s[2][2];
    s[0][0] = mfma16(qf[0], kf[0], zz);
    s[0][1] = mfma16(qf[0], kf[1], zz);
    s[1][0] = mfma16(qf[1], kf[0], zz);
    s[1][1] = mfma16(qf[1], kf[1], zz);

    // scale, distance bias, adjacency mask
    #pragma unroll
    for (int qi = 0; qi < 2; ++qi) {
      const int qq = q0 + qi * 16 + lg * 4;
      #pragma unroll
      for (int ki = 0; ki < 2; ++ki) {
        const int kk = k0 + ki * 16 + lr;
        #pragma unroll
        for (int i = 0; i < 4; ++i) {
          const size_t off = (size_t)(qq + i) * 1024 + kk;
          float sv = s[qi][ki][i] * scale - ds * Db[off];
          sv = (Ab[off] <= 0) ? -1e9f : sv;
          s[qi][ki][i] = sv;
        }
      }
    }

    float p[2][2][4];
    #pragma unroll
    for (int qi = 0; qi < 2; ++qi) {
      #pragma unroll
      for (int i = 0; i < 4; ++i) {
        float rmax = fmaxf(s[qi][0][i], s[qi][1][i]);
        #pragma unroll
        for (int off = 1; off < 16; off <<= 1)
          rmax = fmaxf(rmax, __shfl_xor(rmax, off));
        const float mn = fmaxf(m[qi][i], rmax);
        const float f = __expf(m[qi][i] - mn);
        m[qi][i] = mn;
        float psum = 0.f;
        #pragma unroll
        for (int ki = 0; ki < 2; ++ki) {
          const float pv = __expf(s[qi][ki][i] - mn);
          p[qi][ki][i] = pv;
          psum += pv;
        }
        #pragma unroll
        for (int off = 1; off < 16; off <<= 1)
          psum += __shfl_xor(psum, off);
        l[qi][i] = l[qi][i] * f + psum;
        o[qi][0][i] *= f;
        o[qi][1][i] *= f;
      }
    }

    // P -> LDS (transpose for the PV A-fragment)
    #pragma unroll
    for (int qi = 0; qi < 2; ++qi)
      #pragma unroll
      for (int ki = 0; ki < 2; ++ki)
        #pragma unroll
        for (int i = 0; i < 4; ++i)
          P[h][qi * 16 + lg * 4 + i][ki * 16 + lr] = f2bf(p[qi][ki][i]);
    asm volatile("s_waitcnt lgkmcnt(0)" ::: "memory");
    bf16x8 pf0 = *reinterpret_cast<const bf16x8*>(&P[h][lr][lg * 8]);
    bf16x8 pf1 = *reinterpret_cast<const bf16x8*>(&P[h][16 + lr][lg * 8]);
    o[0][0] = mfma16(pf0, vf[0], o[0][0]);
    o[0][1] = mfma16(pf0, vf[1], o[0][1]);
    o[1][0] = mfma16(pf1, vf[0], o[1][0]);
    o[1][1] = mfma16(pf1, vf[1], o[1][1]);
  }

  #pragma unroll
  for (int qi = 0; qi < 2; ++qi)
    #pragma unroll
    for (int di = 0; di < 2; ++di)
      #pragma unroll
      for (int i = 0; i < 4; ++i) {
        const float val = o[qi][di][i] / l[qi][i];
        const int row = (b << 10) + q0 + qi * 16 + lg * 4 + i;
        const int col = h * 32 + di * 16 + lr;
        AO[row * 256 + col] = f2bf(val);
      }
}

// ---------------- output projection -------------------------------------------
__global__ __launch_bounds__(256) void k_oproj(
    const unsigned short* __restrict__ AO, const unsigned short* __restrict__ Wto,
    const float* __restrict__ bo, float* __restrict__ out) {
  const int lane = threadIdx.x & 63;
  const int w = threadIdx.x >> 6;
  const int lr = lane & 15, lg = lane >> 4;
  const int m0 = blockIdx.x << 5;

  bf16x8 a[2][8];
  #pragma unroll
  for (int mi = 0; mi < 2; ++mi)
    #pragma unroll
    for (int ks = 0; ks < 8; ++ks)
      a[mi][ks] = ldfrag(AO + (m0 + mi * 16 + lr) * 256 + ks * 32 + lg * 8);

  #pragma unroll
  for (int nb = 0; nb < 4; ++nb) {
    const int c0 = nb * 64 + w * 16;
    bf16x8 bfr[8];
    #pragma unroll
    for (int ks = 0; ks < 8; ++ks)
      bfr[ks] = ldfrag(Wto + (c0 + lr) * 256 + ks * 32 + lg * 8);
    f32x4 acc0 = {0.f, 0.f, 0.f, 0.f}, acc1 = {0.f, 0.f, 0.f, 0.f};
    #pragma unroll
    for (int ks = 0; ks < 8; ++ks) {
      acc0 = mfma16(a[0][ks], bfr[ks], acc0);
      acc1 = mfma16(a[1][ks], bfr[ks], acc1);
    }
    const float bb = bo[c0 + lr];
    #pragma unroll
    for (int mi = 0; mi < 2; ++mi) {
      f32x4 acc = mi ? acc1 : acc0;
      #pragma unroll
      for (int i = 0; i < 4; ++i) {
        const int row = m0 + mi * 16 + lg * 4 + i;
        out[row * 256 + c0 + lr] = acc[i] + bb;
      }
    }
  }
}

extern "C" void kernel_launch(void* const* d_in, const int* in_sizes, int n_in,
                              void* d_out, int out_size, void* d_ws, size_t ws_size,
                              hipStream_t stream) {
  const float* X   = (const float*)d_in[0];
  const int*   A   = (const int*)d_in[1];
  const float* D   = (const float*)d_in[2];
  const float* Wq  = (const float*)d_in[3];
  const float* bq  = (const float*)d_in[4];
  const float* Wk  = (const float*)d_in[5];
  const float* bk  = (const float*)d_in[6];
  const float* Wv  = (const float*)d_in[7];
  const float* bv  = (const float*)d_in[8];
  const float* Wo  = (const float*)d_in[9];
  const float* bo  = (const float*)d_in[10];
  const float* dsc = (const float*)d_in[11];
  float* out = (float*)d_out;

  unsigned short* ws = (unsigned short*)d_ws;
  unsigned short* Xbf = ws;                    // 2,097,152
  unsigned short* Wt  = ws + 2097152;          //   262,144 (Wq,Wk,Wv,Wo transposed)
  unsigned short* Qb  = ws + 2359296;          // 2,097,152
  unsigned short* Kb  = ws + 4456448;          // 2,097,152
  unsigned short* Vt  = ws + 6553600;          // 2,097,152
  unsigned short* AO  = ws + 8650752;          // 2,097,152  (total ~21.5 MB)

  hipLaunchKernelGGL(k_prep, dim3(3072), dim3(256), 0, stream,
                     X, Wq, Wk, Wv, Wo, Xbf, Wt);
  hipLaunchKernelGGL(k_qkv, dim3(256), dim3(256), 0, stream,
                     Xbf, Wt, bq, bk, bv, Qb, Kb, Vt);
  hipLaunchKernelGGL(k_attn, dim3(256), dim3(512), 0, stream,
                     Qb, Kb, Vt, A, D, dsc, AO);
  hipLaunchKernelGGL(k_oproj, dim3(256), dim3(256), 0, stream,
                     AO, Wt + 196608, bo, out);
}

// Round 2
// 155.488 us; speedup vs baseline: 1.3067x; 1.3067x over previous
//
#include <hip/hip_runtime.h>

// MultiHeadGraphAttention: B=8, N=1024, IN=OUT=256, H=8, d_k=32
// prep(cvt) -> QKV gemm (bf16 MFMA) -> fused masked attention (S^T trick) -> out proj.

typedef __bf16 bf16x8 __attribute__((ext_vector_type(8)));
typedef float f32x4 __attribute__((ext_vector_type(4)));
typedef int i32x4 __attribute__((ext_vector_type(4)));

#define DEV static __device__ __forceinline__

DEV unsigned short f2bf(float f) {   // RNE f32 -> bf16 bits
  union { float f; unsigned u; } x; x.f = f;
  unsigned r = x.u + 0x7fffu + ((x.u >> 16) & 1u);
  return (unsigned short)(r >> 16);
}

DEV f32x4 mfma16(bf16x8 a, bf16x8 b, f32x4 c) {
  return __builtin_amdgcn_mfma_f32_16x16x32_bf16(a, b, c, 0, 0, 0);
}

DEV bf16x8 ldfrag(const unsigned short* p) {
  return *reinterpret_cast<const bf16x8*>(p);
}

// ---------------- prep: X f32->bf16 ; W_{q,k,v,o} -> bf16 transposed [n][k] ----
__global__ __launch_bounds__(256) void k_prep(
    const float* __restrict__ X,
    const float* __restrict__ Wq, const float* __restrict__ Wk,
    const float* __restrict__ Wv, const float* __restrict__ Wo,
    unsigned short* __restrict__ Xbf, unsigned short* __restrict__ Wt) {
  const int tid = blockIdx.x * 256 + threadIdx.x;
  const int NX4 = (8192 * 256) / 4;           // 524288 float4s of X
  if (tid < NX4) {
    float4 v = reinterpret_cast<const float4*>(X)[tid];
    ushort4 o;
    o.x = f2bf(v.x); o.y = f2bf(v.y); o.z = f2bf(v.z); o.w = f2bf(v.w);
    reinterpret_cast<ushort4*>(Xbf)[tid] = o;
  } else {
    int t = tid - NX4;                        // 0 .. 262143
    int mat = t >> 16;
    int e = t & 65535;
    int n = e >> 8, k = e & 255;              // output Wt[mat][n][k]
    const float* W = (mat == 0) ? Wq : (mat == 1) ? Wk : (mat == 2) ? Wv : Wo;
    Wt[t] = f2bf(W[k * 256 + n]);
  }
}

// ---------------- QKV projection GEMM -----------------------------------------
// grid 512 (m-tiles of 16), block 256 (4 waves). Wave w covers 16 cols of each
// 64-col slab. Outputs: Q,K as [B,H,N,32] bf16; V transposed as [B,H,32,N] bf16.
__global__ __launch_bounds__(256, 2) void k_qkv(
    const unsigned short* __restrict__ Xbf, const unsigned short* __restrict__ Wt,
    const float* __restrict__ bq, const float* __restrict__ bk,
    const float* __restrict__ bv,
    unsigned short* __restrict__ Qb, unsigned short* __restrict__ Kb,
    unsigned short* __restrict__ Vt) {
  const int lane = threadIdx.x & 63;
  const int w = threadIdx.x >> 6;
  const int lr = lane & 15, lg = lane >> 4;
  const int m0 = blockIdx.x << 4;

  bf16x8 a[8];
  #pragma unroll
  for (int ks = 0; ks < 8; ++ks)
    a[ks] = ldfrag(Xbf + (m0 + lr) * 256 + ks * 32 + lg * 8);

  for (int nb = 0; nb < 12; ++nb) {
    const int c0 = nb * 64 + w * 16;          // global col in [0,768)
    const int mat = c0 >> 8;                  // 0=Q 1=K 2=V
    const int nloc = c0 & 255;
    const unsigned short* Wm = Wt + mat * 65536;
    bf16x8 bfr[8];
    #pragma unroll
    for (int ks = 0; ks < 8; ++ks)
      bfr[ks] = ldfrag(Wm + (nloc + lr) * 256 + ks * 32 + lg * 8);
    f32x4 acc = {0.f, 0.f, 0.f, 0.f};
    #pragma unroll
    for (int ks = 0; ks < 8; ++ks)
      acc = mfma16(a[ks], bfr[ks], acc);
    const float* bias = (mat == 0) ? bq : (mat == 1) ? bk : bv;
    const float bb = bias[nloc + lr];
    const int cm = nloc + lr;                 // col within the 256-wide matrix
    const int hh = cm >> 5, d = cm & 31;
    if (mat == 2) {                           // V transposed: 4 consecutive halfs
      ushort4 vv;
      unsigned short* vp = (unsigned short*)&vv;
      #pragma unroll
      for (int i = 0; i < 4; ++i) vp[i] = f2bf(acc[i] + bb);
      const int row = m0 + lg * 4;
      const int bidx = row >> 10, nn = row & 1023;
      *reinterpret_cast<ushort4*>(&Vt[(((bidx * 8 + hh) * 32) + d) * 1024 + nn]) = vv;
    } else {
      #pragma unroll
      for (int i = 0; i < 4; ++i) {
        const int row = m0 + lg * 4 + i;
        const int bidx = row >> 10, nn = row & 1023;
        const unsigned short val = f2bf(acc[i] + bb);
        if (mat == 0)
          Qb[(((bidx * 8 + hh) * 1024) + nn) * 32 + d] = val;
        else
          Kb[(((bidx * 8 + hh) * 1024) + nn) * 32 + d] = val;
      }
    }
  }
}

// ---------------- fused masked attention --------------------------------------
// grid = B * N/16 = 512 blocks, block = 512 threads = 8 waves, wave = head.
// S^T trick: s = mfma(K_frag, Q_frag) puts q in lane dim -> vectorized A/D
// loads (float4/int4) and a 2-shuffle online softmax per tile.
__global__ __launch_bounds__(512, 4) void k_attn(
    const unsigned short* __restrict__ Qb, const unsigned short* __restrict__ Kb,
    const unsigned short* __restrict__ Vt, const int* __restrict__ A,
    const float* __restrict__ D, const float* __restrict__ dscale,
    unsigned short* __restrict__ AO) {
  __shared__ unsigned short P[8][16][40];
  const int lane = threadIdx.x & 63;
  const int h = threadIdx.x >> 6;
  const int lr = lane & 15, lg = lane >> 4;
  const int b = blockIdx.x >> 6;
  const int q0 = (blockIdx.x & 63) << 4;
  const float ds = dscale[0];
  const float scale = 0.17677669529663689f;   // 1/sqrt(32)

  const unsigned short* Qh = Qb + (size_t)((b * 8 + h) * 1024) * 32;
  const unsigned short* Kh = Kb + (size_t)((b * 8 + h) * 1024) * 32;
  const unsigned short* Vh = Vt + (size_t)((b * 8 + h) * 32) * 1024;
  const float* Drow = D + ((size_t)b << 20) + (size_t)(q0 + lr) * 1024;
  const int*   Arow = A + ((size_t)b << 20) + (size_t)(q0 + lr) * 1024;

  const bf16x8 qf = ldfrag(Qh + (q0 + lr) * 32 + lg * 8);

  f32x4 o0 = {0.f, 0.f, 0.f, 0.f}, o1 = {0.f, 0.f, 0.f, 0.f};
  float m = -1e30f, l = 0.f;

  #pragma unroll 2
  for (int kt = 0; kt < 32; ++kt) {
    const int k0 = kt << 5;
    const bf16x8 kf0 = ldfrag(Kh + (k0 + lr) * 32 + lg * 8);
    const bf16x8 kf1 = ldfrag(Kh + (k0 + 16 + lr) * 32 + lg * 8);
    const bf16x8 vf0 = ldfrag(Vh + lr * 1024 + k0 + lg * 8);
    const bf16x8 vf1 = ldfrag(Vh + (16 + lr) * 1024 + k0 + lg * 8);
    const f32x4 dd0 = *reinterpret_cast<const f32x4*>(Drow + k0 + lg * 4);
    const f32x4 dd1 = *reinterpret_cast<const f32x4*>(Drow + k0 + 16 + lg * 4);
    const i32x4 aa0 = *reinterpret_cast<const i32x4*>(Arow + k0 + lg * 4);
    const i32x4 aa1 = *reinterpret_cast<const i32x4*>(Arow + k0 + 16 + lg * 4);

    const f32x4 zz = {0.f, 0.f, 0.f, 0.f};
    f32x4 s0 = mfma16(kf0, qf, zz);   // S^T: row = k0+lg*4+i, col(lane) = q0+lr
    f32x4 s1 = mfma16(kf1, qf, zz);

    #pragma unroll
    for (int i = 0; i < 4; ++i) {
      s0[i] = (aa0[i] <= 0) ? -1e9f : s0[i] * scale - ds * dd0[i];
      s1[i] = (aa1[i] <= 0) ? -1e9f : s1[i] * scale - ds * dd1[i];
    }

    float tmax = fmaxf(fmaxf(fmaxf(s0[0], s0[1]), fmaxf(s0[2], s0[3])),
                       fmaxf(fmaxf(s1[0], s1[1]), fmaxf(s1[2], s1[3])));
    tmax = fmaxf(tmax, __shfl_xor(tmax, 16));
    tmax = fmaxf(tmax, __shfl_xor(tmax, 32));
    const float mn = fmaxf(m, tmax);
    const float f = __expf(m - mn);
    m = mn;

    float p0[4], p1[4];
    float psum = 0.f;
    #pragma unroll
    for (int i = 0; i < 4; ++i) {
      p0[i] = __expf(s0[i] - mn);
      p1[i] = __expf(s1[i] - mn);
      psum += p0[i] + p1[i];
    }
    psum += __shfl_xor(psum, 16);
    psum += __shfl_xor(psum, 32);
    l = l * f + psum;

    // P[q=lr][k] -> LDS, two 8B vector writes (k contiguous per lane)
    ushort4 w0, w1;
    unsigned short* w0p = (unsigned short*)&w0;
    unsigned short* w1p = (unsigned short*)&w1;
    #pragma unroll
    for (int i = 0; i < 4; ++i) { w0p[i] = f2bf(p0[i]); w1p[i] = f2bf(p1[i]); }
    *reinterpret_cast<ushort4*>(&P[h][lr][lg * 4]) = w0;
    *reinterpret_cast<ushort4*>(&P[h][lr][16 + lg * 4]) = w1;

    // rescale O: rows of O are q = lg*4+ii -> broadcast f from lane lr'=lg*4+ii
    #pragma unroll
    for (int ii = 0; ii < 4; ++ii) {
      const float fb = __shfl(f, lg * 4 + ii);
      o0[ii] *= fb;
      o1[ii] *= fb;
    }

    const bf16x8 pf = *reinterpret_cast<const bf16x8*>(&P[h][lr][lg * 8]);
    o0 = mfma16(pf, vf0, o0);
    o1 = mfma16(pf, vf1, o1);
  }

  #pragma unroll
  for (int ii = 0; ii < 4; ++ii) {
    const float lb = __shfl(l, lg * 4 + ii);
    const float linv = 1.0f / lb;
    const int row = (b << 10) + q0 + lg * 4 + ii;
    AO[row * 256 + h * 32 + lr]      = f2bf(o0[ii] * linv);
    AO[row * 256 + h * 32 + 16 + lr] = f2bf(o1[ii] * linv);
  }
}

// ---------------- output projection -------------------------------------------
__global__ __launch_bounds__(256, 2) void k_oproj(
    const unsigned short* __restrict__ AO, const unsigned short* __restrict__ Wto,
    const float* __restrict__ bo, float* __restrict__ out) {
  const int lane = threadIdx.x & 63;
  const int w = threadIdx.x >> 6;
  const int lr = lane & 15, lg = lane >> 4;
  const int m0 = blockIdx.x << 4;

  bf16x8 a[8];
  #pragma unroll
  for (int ks = 0; ks < 8; ++ks)
    a[ks] = ldfrag(AO + (m0 + lr) * 256 + ks * 32 + lg * 8);

  #pragma unroll
  for (int nb = 0; nb < 4; ++nb) {
    const int c0 = nb * 64 + w * 16;
    bf16x8 bfr[8];
    #pragma unroll
    for (int ks = 0; ks < 8; ++ks)
      bfr[ks] = ldfrag(Wto + (c0 + lr) * 256 + ks * 32 + lg * 8);
    f32x4 acc = {0.f, 0.f, 0.f, 0.f};
    #pragma unroll
    for (int ks = 0; ks < 8; ++ks)
      acc = mfma16(a[ks], bfr[ks], acc);
    const float bb = bo[c0 + lr];
    #pragma unroll
    for (int i = 0; i < 4; ++i) {
      const int row = m0 + lg * 4 + i;
      out[row * 256 + c0 + lr] = acc[i] + bb;
    }
  }
}

extern "C" void kernel_launch(void* const* d_in, const int* in_sizes, int n_in,
                              void* d_out, int out_size, void* d_ws, size_t ws_size,
                              hipStream_t stream) {
  const float* X   = (const float*)d_in[0];
  const int*   A   = (const int*)d_in[1];
  const float* D   = (const float*)d_in[2];
  const float* Wq  = (const float*)d_in[3];
  const float* bq  = (const float*)d_in[4];
  const float* Wk  = (const float*)d_in[5];
  const float* bk  = (const float*)d_in[6];
  const float* Wv  = (const float*)d_in[7];
  const float* bv  = (const float*)d_in[8];
  const float* Wo  = (const float*)d_in[9];
  const float* bo  = (const float*)d_in[10];
  const float* dsc = (const float*)d_in[11];
  float* out = (float*)d_out;

  unsigned short* ws = (unsigned short*)d_ws;
  unsigned short* Xbf = ws;                    // 2,097,152
  unsigned short* Wt  = ws + 2097152;          //   262,144 (Wq,Wk,Wv,Wo transposed)
  unsigned short* Qb  = ws + 2359296;          // 2,097,152
  unsigned short* Kb  = ws + 4456448;          // 2,097,152
  unsigned short* Vt  = ws + 6553600;          // 2,097,152
  unsigned short* AO  = ws + 8650752;          // 2,097,152  (total ~21.5 MB)

  hipLaunchKernelGGL(k_prep, dim3(3072), dim3(256), 0, stream,
                     X, Wq, Wk, Wv, Wo, Xbf, Wt);
  hipLaunchKernelGGL(k_qkv, dim3(512), dim3(256), 0, stream,
                     Xbf, Wt, bq, bk, bv, Qb, Kb, Vt);
  hipLaunchKernelGGL(k_attn, dim3(512), dim3(512), 0, stream,
                     Qb, Kb, Vt, A, D, dsc, AO);
  hipLaunchKernelGGL(k_oproj, dim3(512), dim3(256), 0, stream,
                     AO, Wt + 196608, bo, out);
}

// Round 3
// 139.386 us; speedup vs baseline: 1.4577x; 1.1155x over previous
//
#include <hip/hip_runtime.h>

// MultiHeadGraphAttention: B=8, N=1024, IN=OUT=256, H=8, d_k=32
// prep(cvt + fused mask/dist bias in fp16) -> QKV gemm (bf16 MFMA, Q pre-scaled)
// -> fused masked attention (S^T + O^T tricks, exp2 domain, prefetch pipeline)
// -> out proj.

typedef __bf16 bf16x8 __attribute__((ext_vector_type(8)));
typedef float f32x4 __attribute__((ext_vector_type(4)));
typedef int i32x4 __attribute__((ext_vector_type(4)));

#define DEV static __device__ __forceinline__

#define LOG2E 1.4426950408889634f
#define QSCALE 0.2550351062f   // (1/sqrt(32)) * log2(e)

DEV unsigned short f2bf(float f) {   // RNE f32 -> bf16 bits
  union { float f; unsigned u; } x; x.f = f;
  unsigned r = x.u + 0x7fffu + ((x.u >> 16) & 1u);
  return (unsigned short)(r >> 16);
}

DEV unsigned short f2h(float f) {    // f32 -> fp16 bits (RNE)
  _Float16 h = (_Float16)f;
  unsigned short u;
  __builtin_memcpy(&u, &h, 2);
  return u;
}

DEV float h2f(unsigned short u) {    // fp16 bits -> f32
  _Float16 h;
  __builtin_memcpy(&h, &u, 2);
  return (float)h;
}

DEV f32x4 mfma16(bf16x8 a, bf16x8 b, f32x4 c) {
  return __builtin_amdgcn_mfma_f32_16x16x32_bf16(a, b, c, 0, 0, 0);
}

DEV bf16x8 ldfrag(const unsigned short* p) {
  return *reinterpret_cast<const bf16x8*>(p);
}

// ---------------- prep ---------------------------------------------------------
// range 0: Bias[b][q][k] fp16 = A<=0 ? -60000 : -ds*log2e*D   (4 elems/thread)
// range 1: X f32 -> bf16
// range 2: W_{q,k,v,o} -> bf16 transposed [n][k]
__global__ __launch_bounds__(256) void k_prep(
    const float* __restrict__ X, const int* __restrict__ A,
    const float* __restrict__ D, const float* __restrict__ dscale,
    const float* __restrict__ Wq, const float* __restrict__ Wk,
    const float* __restrict__ Wv, const float* __restrict__ Wo,
    unsigned short* __restrict__ Xbf, unsigned short* __restrict__ Wt,
    unsigned short* __restrict__ Bias) {
  const int tid = blockIdx.x * 256 + threadIdx.x;
  const int NB4 = (8 * 1024 * 1024) / 4;      // 2,097,152 bias quads
  const int NX4 = (8192 * 256) / 4;           //   524,288 X quads
  if (tid < NB4) {
    const i32x4 a4 = reinterpret_cast<const i32x4*>(A)[tid];
    const f32x4 d4 = reinterpret_cast<const f32x4*>(D)[tid];
    const float c = -dscale[0] * LOG2E;
    ushort4 o;
    unsigned short* op = (unsigned short*)&o;
    #pragma unroll
    for (int i = 0; i < 4; ++i)
      op[i] = f2h(a4[i] <= 0 ? -60000.0f : c * d4[i]);
    reinterpret_cast<ushort4*>(Bias)[tid] = o;
  } else if (tid < NB4 + NX4) {
    const int t = tid - NB4;
    float4 v = reinterpret_cast<const float4*>(X)[t];
    ushort4 o;
    o.x = f2bf(v.x); o.y = f2bf(v.y); o.z = f2bf(v.z); o.w = f2bf(v.w);
    reinterpret_cast<ushort4*>(Xbf)[t] = o;
  } else {
    int t = tid - NB4 - NX4;                  // 0 .. 262143
    int mat = t >> 16;
    int e = t & 65535;
    int n = e >> 8, k = e & 255;              // output Wt[mat][n][k]
    const float* W = (mat == 0) ? Wq : (mat == 1) ? Wk : (mat == 2) ? Wv : Wo;
    Wt[t] = f2bf(W[k * 256 + n]);
  }
}

// ---------------- QKV projection GEMM -----------------------------------------
// grid 512 (m-tiles of 16), block 256 (4 waves). Q written pre-scaled by QSCALE.
// Outputs: Q,K as [B,H,N,32] bf16; V transposed as [B,H,32,N] bf16.
__global__ __launch_bounds__(256, 2) void k_qkv(
    const unsigned short* __restrict__ Xbf, const unsigned short* __restrict__ Wt,
    const float* __restrict__ bq, const float* __restrict__ bk,
    const float* __restrict__ bv,
    unsigned short* __restrict__ Qb, unsigned short* __restrict__ Kb,
    unsigned short* __restrict__ Vt) {
  const int lane = threadIdx.x & 63;
  const int w = threadIdx.x >> 6;
  const int lr = lane & 15, lg = lane >> 4;
  const int m0 = blockIdx.x << 4;

  bf16x8 a[8];
  #pragma unroll
  for (int ks = 0; ks < 8; ++ks)
    a[ks] = ldfrag(Xbf + (m0 + lr) * 256 + ks * 32 + lg * 8);

  for (int nb = 0; nb < 12; ++nb) {
    const int c0 = nb * 64 + w * 16;          // global col in [0,768)
    const int mat = c0 >> 8;                  // 0=Q 1=K 2=V
    const int nloc = c0 & 255;
    const unsigned short* Wm = Wt + mat * 65536;
    bf16x8 bfr[8];
    #pragma unroll
    for (int ks = 0; ks < 8; ++ks)
      bfr[ks] = ldfrag(Wm + (nloc + lr) * 256 + ks * 32 + lg * 8);
    f32x4 acc = {0.f, 0.f, 0.f, 0.f};
    #pragma unroll
    for (int ks = 0; ks < 8; ++ks)
      acc = mfma16(a[ks], bfr[ks], acc);
    const float* bias = (mat == 0) ? bq : (mat == 1) ? bk : bv;
    const float bb = bias[nloc + lr];
    const int cm = nloc + lr;                 // col within the 256-wide matrix
    const int hh = cm >> 5, d = cm & 31;
    if (mat == 2) {                           // V transposed: 4 consecutive halfs
      ushort4 vv;
      unsigned short* vp = (unsigned short*)&vv;
      #pragma unroll
      for (int i = 0; i < 4; ++i) vp[i] = f2bf(acc[i] + bb);
      const int row = m0 + lg * 4;
      const int bidx = row >> 10, nn = row & 1023;
      *reinterpret_cast<ushort4*>(&Vt[(((bidx * 8 + hh) * 32) + d) * 1024 + nn]) = vv;
    } else if (mat == 0) {
      #pragma unroll
      for (int i = 0; i < 4; ++i) {
        const int row = m0 + lg * 4 + i;
        const int bidx = row >> 10, nn = row & 1023;
        Qb[(((bidx * 8 + hh) * 1024) + nn) * 32 + d] = f2bf((acc[i] + bb) * QSCALE);
      }
    } else {
      #pragma unroll
      for (int i = 0; i < 4; ++i) {
        const int row = m0 + lg * 4 + i;
        const int bidx = row >> 10, nn = row & 1023;
        Kb[(((bidx * 8 + hh) * 1024) + nn) * 32 + d] = f2bf(acc[i] + bb);
      }
    }
  }
}

// ---------------- fused masked attention --------------------------------------
// grid = B * N/16 = 512 blocks, block = 512 threads = 8 waves, wave = head.
// S^T trick (q in lane dim) + O^T trick (mfma(vf,pf): O cols = q = lane) ->
// softmax state, rescale, and epilogue all per-lane, zero broadcast shuffles.
// exp2 domain; Bias fp16 preloaded; dist-1 prefetch K/V, dist-2 prefetch Bias.
__global__ __launch_bounds__(512, 4) void k_attn(
    const unsigned short* __restrict__ Qb, const unsigned short* __restrict__ Kb,
    const unsigned short* __restrict__ Vt, const unsigned short* __restrict__ Bias,
    unsigned short* __restrict__ AO) {
  __shared__ unsigned short P[8][16][44];
  const int lane = threadIdx.x & 63;
  const int h = threadIdx.x >> 6;
  const int lr = lane & 15, lg = lane >> 4;
  const int b = blockIdx.x >> 6;
  const int q0 = (blockIdx.x & 63) << 4;

  const unsigned short* Qh = Qb + (size_t)((b * 8 + h) * 1024) * 32;
  const unsigned short* Kh = Kb + (size_t)((b * 8 + h) * 1024) * 32;
  const unsigned short* Vh = Vt + (size_t)((b * 8 + h) * 32) * 1024;
  const unsigned short* Brow = Bias + ((size_t)b << 20) + (size_t)(q0 + lr) * 1024;

  const bf16x8 qf = ldfrag(Qh + (q0 + lr) * 32 + lg * 8);

  f32x4 o0 = {0.f, 0.f, 0.f, 0.f}, o1 = {0.f, 0.f, 0.f, 0.f};
  float m = -1e30f, l = 0.f;

  // prefetch: tile 0 K/V, tiles 0-1 bias
  bf16x8 kf0 = ldfrag(Kh + lr * 32 + lg * 8);
  bf16x8 kf1 = ldfrag(Kh + (16 + lr) * 32 + lg * 8);
  bf16x8 vf0 = ldfrag(Vh + lr * 1024 + lg * 8);
  bf16x8 vf1 = ldfrag(Vh + (16 + lr) * 1024 + lg * 8);
  ushort4 ba0 = *reinterpret_cast<const ushort4*>(Brow + lg * 4);
  ushort4 ba1 = *reinterpret_cast<const ushort4*>(Brow + 16 + lg * 4);
  ushort4 bb0 = *reinterpret_cast<const ushort4*>(Brow + 32 + lg * 4);
  ushort4 bb1 = *reinterpret_cast<const ushort4*>(Brow + 48 + lg * 4);

  #pragma unroll 2
  for (int kt = 0; kt < 32; ++kt) {
    const int kn1 = ((kt + 1) & 31) << 5;     // next tile (K/V)
    const int kn2 = ((kt + 2) & 31) << 5;     // next-next tile (bias)
    bf16x8 kf0n = ldfrag(Kh + (kn1 + lr) * 32 + lg * 8);
    bf16x8 kf1n = ldfrag(Kh + (kn1 + 16 + lr) * 32 + lg * 8);
    bf16x8 vf0n = ldfrag(Vh + lr * 1024 + kn1 + lg * 8);
    bf16x8 vf1n = ldfrag(Vh + (16 + lr) * 1024 + kn1 + lg * 8);
    ushort4 bn0 = *reinterpret_cast<const ushort4*>(Brow + kn2 + lg * 4);
    ushort4 bn1 = *reinterpret_cast<const ushort4*>(Brow + kn2 + 16 + lg * 4);

    const f32x4 zz = {0.f, 0.f, 0.f, 0.f};
    f32x4 s0 = mfma16(kf0, qf, zz);   // S^T: row = k (reg), col = q (lane lr)
    f32x4 s1 = mfma16(kf1, qf, zz);

    const unsigned short* a0p = (const unsigned short*)&ba0;
    const unsigned short* a1p = (const unsigned short*)&ba1;
    float sf0[4], sf1[4];
    #pragma unroll
    for (int i = 0; i < 4; ++i) {
      sf0[i] = s0[i] + h2f(a0p[i]);
      sf1[i] = s1[i] + h2f(a1p[i]);
    }

    float tmax = fmaxf(fmaxf(fmaxf(sf0[0], sf0[1]), fmaxf(sf0[2], sf0[3])),
                       fmaxf(fmaxf(sf1[0], sf1[1]), fmaxf(sf1[2], sf1[3])));
    tmax = fmaxf(tmax, __shfl_xor(tmax, 16));
    tmax = fmaxf(tmax, __shfl_xor(tmax, 32));
    const float mn = fmaxf(m, tmax);
    const float f = exp2f(m - mn);
    m = mn;

    float p0[4], p1[4];
    float psum = 0.f;
    #pragma unroll
    for (int i = 0; i < 4; ++i) {
      p0[i] = exp2f(sf0[i] - mn);
      p1[i] = exp2f(sf1[i] - mn);
      psum += p0[i] + p1[i];
    }
    psum += __shfl_xor(psum, 16);
    psum += __shfl_xor(psum, 32);
    l = l * f + psum;

    // P[q=lr][k] -> LDS (two 8B writes), read back as PV B-fragment
    ushort4 w0, w1;
    unsigned short* w0p = (unsigned short*)&w0;
    unsigned short* w1p = (unsigned short*)&w1;
    #pragma unroll
    for (int i = 0; i < 4; ++i) { w0p[i] = f2bf(p0[i]); w1p[i] = f2bf(p1[i]); }
    *reinterpret_cast<ushort4*>(&P[h][lr][lg * 4]) = w0;
    *reinterpret_cast<ushort4*>(&P[h][lr][16 + lg * 4]) = w1;

    // rescale O^T: cols = q = lane -> per-lane multiply, no shuffles
    #pragma unroll
    for (int i = 0; i < 4; ++i) { o0[i] *= f; o1[i] *= f; }

    const bf16x8 pf = *reinterpret_cast<const bf16x8*>(&P[h][lr][lg * 8]);
    o0 = mfma16(vf0, pf, o0);   // O^T: row = d (reg), col = q (lane lr)
    o1 = mfma16(vf1, pf, o1);

    kf0 = kf0n; kf1 = kf1n; vf0 = vf0n; vf1 = vf1n;
    ba0 = bb0; ba1 = bb1; bb0 = bn0; bb1 = bn1;
  }

  const float linv = 1.0f / l;                // per-lane (q = lr)
  ushort4 r0, r1;
  unsigned short* r0p = (unsigned short*)&r0;
  unsigned short* r1p = (unsigned short*)&r1;
  #pragma unroll
  for (int i = 0; i < 4; ++i) {
    r0p[i] = f2bf(o0[i] * linv);
    r1p[i] = f2bf(o1[i] * linv);
  }
  const int row = (b << 10) + q0 + lr;
  *reinterpret_cast<ushort4*>(&AO[row * 256 + h * 32 + lg * 4]) = r0;
  *reinterpret_cast<ushort4*>(&AO[row * 256 + h * 32 + 16 + lg * 4]) = r1;
}

// ---------------- output projection -------------------------------------------
__global__ __launch_bounds__(256, 2) void k_oproj(
    const unsigned short* __restrict__ AO, const unsigned short* __restrict__ Wto,
    const float* __restrict__ bo, float* __restrict__ out) {
  const int lane = threadIdx.x & 63;
  const int w = threadIdx.x >> 6;
  const int lr = lane & 15, lg = lane >> 4;
  const int m0 = blockIdx.x << 4;

  bf16x8 a[8];
  #pragma unroll
  for (int ks = 0; ks < 8; ++ks)
    a[ks] = ldfrag(AO + (m0 + lr) * 256 + ks * 32 + lg * 8);

  #pragma unroll
  for (int nb = 0; nb < 4; ++nb) {
    const int c0 = nb * 64 + w * 16;
    bf16x8 bfr[8];
    #pragma unroll
    for (int ks = 0; ks < 8; ++ks)
      bfr[ks] = ldfrag(Wto + (c0 + lr) * 256 + ks * 32 + lg * 8);
    f32x4 acc = {0.f, 0.f, 0.f, 0.f};
    #pragma unroll
    for (int ks = 0; ks < 8; ++ks)
      acc = mfma16(a[ks], bfr[ks], acc);
    const float bb = bo[c0 + lr];
    #pragma unroll
    for (int i = 0; i < 4; ++i) {
      const int row = m0 + lg * 4 + i;
      out[row * 256 + c0 + lr] = acc[i] + bb;
    }
  }
}

extern "C" void kernel_launch(void* const* d_in, const int* in_sizes, int n_in,
                              void* d_out, int out_size, void* d_ws, size_t ws_size,
                              hipStream_t stream) {
  const float* X   = (const float*)d_in[0];
  const int*   A   = (const int*)d_in[1];
  const float* D   = (const float*)d_in[2];
  const float* Wq  = (const float*)d_in[3];
  const float* bq  = (const float*)d_in[4];
  const float* Wk  = (const float*)d_in[5];
  const float* bk  = (const float*)d_in[6];
  const float* Wv  = (const float*)d_in[7];
  const float* bv  = (const float*)d_in[8];
  const float* Wo  = (const float*)d_in[9];
  const float* bo  = (const float*)d_in[10];
  const float* dsc = (const float*)d_in[11];
  float* out = (float*)d_out;

  unsigned short* ws = (unsigned short*)d_ws;
  unsigned short* Xbf  = ws;                   // 2,097,152  (reused as AO later)
  unsigned short* Wt   = ws + 2097152;         //   262,144
  unsigned short* Qb   = ws + 2359296;         // 2,097,152
  unsigned short* Kb   = ws + 4456448;         // 2,097,152
  unsigned short* Vt   = ws + 6553600;         // 2,097,152
  unsigned short* Bias = ws + 8650752;         // 8,388,608  (total ~34.1 MB)
  unsigned short* AO   = Xbf;                  // alias: Xbf dead after k_qkv

  hipLaunchKernelGGL(k_prep, dim3(11264), dim3(256), 0, stream,
                     X, A, D, dsc, Wq, Wk, Wv, Wo, Xbf, Wt, Bias);
  hipLaunchKernelGGL(k_qkv, dim3(512), dim3(256), 0, stream,
                     Xbf, Wt, bq, bk, bv, Qb, Kb, Vt);
  hipLaunchKernelGGL(k_attn, dim3(512), dim3(512), 0, stream,
                     Qb, Kb, Vt, Bias, AO);
  hipLaunchKernelGGL(k_oproj, dim3(512), dim3(256), 0, stream,
                     AO, Wt + 196608, bo, out);
}

// Round 4
// 138.121 us; speedup vs baseline: 1.4710x; 1.0092x over previous
//
#include <hip/hip_runtime.h>

// MultiHeadGraphAttention: B=8, N=1024, IN=OUT=256, H=8, d_k=32
// prep(cvt + fused mask/dist bias fp16) -> QKV gemm (bf16 MFMA, Q pre-scaled)
// -> fused masked attention (S^T/O^T, exp2 domain, 64-key pipelined iters,
//    XCD-affine blocks, double-buffered P) -> out proj.

typedef __bf16 bf16x8 __attribute__((ext_vector_type(8)));
typedef float f32x4 __attribute__((ext_vector_type(4)));
typedef int i32x4 __attribute__((ext_vector_type(4)));

#define DEV static __device__ __forceinline__

#define LOG2E 1.4426950408889634f
#define QSCALE 0.2550351062f   // (1/sqrt(32)) * log2(e)

DEV unsigned short f2bf(float f) {   // RNE f32 -> bf16 bits
  union { float f; unsigned u; } x; x.f = f;
  unsigned r = x.u + 0x7fffu + ((x.u >> 16) & 1u);
  return (unsigned short)(r >> 16);
}

DEV unsigned short f2h(float f) {    // f32 -> fp16 bits (RNE)
  _Float16 h = (_Float16)f;
  unsigned short u;
  __builtin_memcpy(&u, &h, 2);
  return u;
}

DEV float h2f(unsigned short u) {    // fp16 bits -> f32
  _Float16 h;
  __builtin_memcpy(&h, &u, 2);
  return (float)h;
}

DEV f32x4 mfma16(bf16x8 a, bf16x8 b, f32x4 c) {
  return __builtin_amdgcn_mfma_f32_16x16x32_bf16(a, b, c, 0, 0, 0);
}

DEV bf16x8 ldfrag(const unsigned short* p) {
  return *reinterpret_cast<const bf16x8*>(p);
}

// ---------------- prep ---------------------------------------------------------
__global__ __launch_bounds__(256) void k_prep(
    const float* __restrict__ X, const int* __restrict__ A,
    const float* __restrict__ D, const float* __restrict__ dscale,
    const float* __restrict__ Wq, const float* __restrict__ Wk,
    const float* __restrict__ Wv, const float* __restrict__ Wo,
    unsigned short* __restrict__ Xbf, unsigned short* __restrict__ Wt,
    unsigned short* __restrict__ Bias) {
  const int tid = blockIdx.x * 256 + threadIdx.x;
  const int NB4 = (8 * 1024 * 1024) / 4;      // 2,097,152 bias quads
  const int NX4 = (8192 * 256) / 4;           //   524,288 X quads
  if (tid < NB4) {
    const i32x4 a4 = reinterpret_cast<const i32x4*>(A)[tid];
    const f32x4 d4 = reinterpret_cast<const f32x4*>(D)[tid];
    const float c = -dscale[0] * LOG2E;
    ushort4 o;
    unsigned short* op = (unsigned short*)&o;
    #pragma unroll
    for (int i = 0; i < 4; ++i)
      op[i] = f2h(a4[i] <= 0 ? -60000.0f : c * d4[i]);
    reinterpret_cast<ushort4*>(Bias)[tid] = o;
  } else if (tid < NB4 + NX4) {
    const int t = tid - NB4;
    float4 v = reinterpret_cast<const float4*>(X)[t];
    ushort4 o;
    o.x = f2bf(v.x); o.y = f2bf(v.y); o.z = f2bf(v.z); o.w = f2bf(v.w);
    reinterpret_cast<ushort4*>(Xbf)[t] = o;
  } else {
    int t = tid - NB4 - NX4;                  // 0 .. 262143
    int mat = t >> 16;
    int e = t & 65535;
    int n = e >> 8, k = e & 255;              // output Wt[mat][n][k]
    const float* W = (mat == 0) ? Wq : (mat == 1) ? Wk : (mat == 2) ? Wv : Wo;
    Wt[t] = f2bf(W[k * 256 + n]);
  }
}

// ---------------- QKV projection GEMM -----------------------------------------
// grid (512, 3): x = m-tile of 16, y = matrix (0=Q 1=K 2=V). block 256 (4 waves),
// wave w covers 16 cols of each 64-col slab. Q pre-scaled by QSCALE.
__global__ __launch_bounds__(256, 2) void k_qkv(
    const unsigned short* __restrict__ Xbf, const unsigned short* __restrict__ Wt,
    const float* __restrict__ bq, const float* __restrict__ bk,
    const float* __restrict__ bv,
    unsigned short* __restrict__ Qb, unsigned short* __restrict__ Kb,
    unsigned short* __restrict__ Vt) {
  const int lane = threadIdx.x & 63;
  const int w = threadIdx.x >> 6;
  const int lr = lane & 15, lg = lane >> 4;
  const int m0 = blockIdx.x << 4;
  const int mat = blockIdx.y;

  bf16x8 a[8];
  #pragma unroll
  for (int ks = 0; ks < 8; ++ks)
    a[ks] = ldfrag(Xbf + (m0 + lr) * 256 + ks * 32 + lg * 8);

  const unsigned short* Wm = Wt + mat * 65536;
  const float* bias = (mat == 0) ? bq : (mat == 1) ? bk : bv;

  #pragma unroll
  for (int nb = 0; nb < 4; ++nb) {
    const int nloc = nb * 64 + w * 16;
    bf16x8 bfr[8];
    #pragma unroll
    for (int ks = 0; ks < 8; ++ks)
      bfr[ks] = ldfrag(Wm + (nloc + lr) * 256 + ks * 32 + lg * 8);
    f32x4 acc = {0.f, 0.f, 0.f, 0.f};
    #pragma unroll
    for (int ks = 0; ks < 8; ++ks)
      acc = mfma16(a[ks], bfr[ks], acc);
    const float bb = bias[nloc + lr];
    const int cm = nloc + lr;
    const int hh = cm >> 5, d = cm & 31;
    if (mat == 2) {                           // V transposed: 4 consecutive halfs
      ushort4 vv;
      unsigned short* vp = (unsigned short*)&vv;
      #pragma unroll
      for (int i = 0; i < 4; ++i) vp[i] = f2bf(acc[i] + bb);
      const int row = m0 + lg * 4;
      const int bidx = row >> 10, nn = row & 1023;
      *reinterpret_cast<ushort4*>(&Vt[(((bidx * 8 + hh) * 32) + d) * 1024 + nn]) = vv;
    } else if (mat == 0) {
      #pragma unroll
      for (int i = 0; i < 4; ++i) {
        const int row = m0 + lg * 4 + i;
        const int bidx = row >> 10, nn = row & 1023;
        Qb[(((bidx * 8 + hh) * 1024) + nn) * 32 + d] = f2bf((acc[i] + bb) * QSCALE);
      }
    } else {
      #pragma unroll
      for (int i = 0; i < 4; ++i) {
        const int row = m0 + lg * 4 + i;
        const int bidx = row >> 10, nn = row & 1023;
        Kb[(((bidx * 8 + hh) * 1024) + nn) * 32 + d] = f2bf(acc[i] + bb);
      }
    }
  }
}

// ---------------- fused masked attention --------------------------------------
// grid 512: b = blockIdx&7 (XCD-affine), q0 = (blockIdx>>3)*16. 8 waves = heads.
// 64 keys/iter, 16 iters. S^T (q in lanes) + O^T (O cols = q). Pipelined:
// K(t+1)/V(t+1)/bias(t+1) prefetched into named regs; P double-buffered in LDS,
// PV lags one iteration so the LDS round-trip overlaps softmax VALU work.
__global__ __launch_bounds__(512, 4) void k_attn(
    const unsigned short* __restrict__ Qb, const unsigned short* __restrict__ Kb,
    const unsigned short* __restrict__ Vt, const unsigned short* __restrict__ Bias,
    unsigned short* __restrict__ AO) {
  __shared__ unsigned short P[8][2][16][72];  // [head][buf][q][64 keys + pad]
  const int lane = threadIdx.x & 63;
  const int h = threadIdx.x >> 6;
  const int lr = lane & 15, lg = lane >> 4;
  const int b = blockIdx.x & 7;               // XCD affinity: batch b -> XCD b
  const int q0 = (blockIdx.x >> 3) << 4;

  const unsigned short* Qh = Qb + (size_t)((b * 8 + h) * 1024) * 32;
  const unsigned short* Kh = Kb + (size_t)((b * 8 + h) * 1024) * 32;
  const unsigned short* Vh = Vt + (size_t)((b * 8 + h) * 32) * 1024;
  const unsigned short* Brow = Bias + ((size_t)b << 20) + (size_t)(q0 + lr) * 1024;

  const bf16x8 qf = ldfrag(Qh + (q0 + lr) * 32 + lg * 8);

  f32x4 o0 = {0.f, 0.f, 0.f, 0.f}, o1 = {0.f, 0.f, 0.f, 0.f};
  float m = -1e30f, l = 0.f;

  // prologue: K(0), V(0), bias(0)
  bf16x8 kf[4], vp[2][2], vn[2][2];
  ushort4 bc[4], bn[4];
  #pragma unroll
  for (int s = 0; s < 4; ++s)
    kf[s] = ldfrag(Kh + (s * 16 + lr) * 32 + lg * 8);
  #pragma unroll
  for (int dh = 0; dh < 2; ++dh)
    #pragma unroll
    for (int ks = 0; ks < 2; ++ks)
      vn[dh][ks] = ldfrag(Vh + (dh * 16 + lr) * 1024 + ks * 32 + lg * 8);
  #pragma unroll
  for (int tt = 0; tt < 4; ++tt)
    bc[tt] = *reinterpret_cast<const ushort4*>(Brow + tt * 16 + lg * 4);

  for (int t = 0; t < 16; ++t) {
    const int k0 = t << 6;
    // issue bias(t+1) early (HBM-cold stream)
    if (t < 15) {
      #pragma unroll
      for (int tt = 0; tt < 4; ++tt)
        bn[tt] = *reinterpret_cast<const ushort4*>(Brow + k0 + 64 + tt * 16 + lg * 4);
    }

    // QK^T: s[st] rows = keys k0+st*16+lg*4+i, cols = q (lane lr)
    const f32x4 zz = {0.f, 0.f, 0.f, 0.f};
    f32x4 s[4];
    #pragma unroll
    for (int st = 0; st < 4; ++st)
      s[st] = mfma16(kf[st], qf, zz);

    // issue K(t+1) (kf consumed by the mfmas above)
    if (t < 15) {
      #pragma unroll
      for (int st = 0; st < 4; ++st)
        kf[st] = ldfrag(Kh + (k0 + 64 + st * 16 + lr) * 32 + lg * 8);
    }

    // issue P(t-1) read early; completes under the softmax below
    bf16x8 pf0, pf1;
    if (t > 0) {
      const unsigned short* pb = &P[h][(t - 1) & 1][lr][0];
      pf0 = *reinterpret_cast<const bf16x8*>(pb + lg * 8);
      pf1 = *reinterpret_cast<const bf16x8*>(pb + 32 + lg * 8);
    }

    // bias add + online softmax stats
    float sf[4][4];
    #pragma unroll
    for (int st = 0; st < 4; ++st) {
      const unsigned short* bp = (const unsigned short*)&bc[st];
      #pragma unroll
      for (int i = 0; i < 4; ++i)
        sf[st][i] = s[st][i] + h2f(bp[i]);
    }
    float tmax = -1e30f;
    #pragma unroll
    for (int st = 0; st < 4; ++st)
      #pragma unroll
      for (int i = 0; i < 4; ++i)
        tmax = fmaxf(tmax, sf[st][i]);
    tmax = fmaxf(tmax, __shfl_xor(tmax, 16));
    tmax = fmaxf(tmax, __shfl_xor(tmax, 32));
    const float mn = fmaxf(m, tmax);
    const float f = exp2f(m - mn);
    m = mn;

    float p[4][4];
    float psum = 0.f;
    #pragma unroll
    for (int st = 0; st < 4; ++st)
      #pragma unroll
      for (int i = 0; i < 4; ++i) {
        p[st][i] = exp2f(sf[st][i] - mn);
        psum += p[st][i];
      }
    psum += __shfl_xor(psum, 16);
    psum += __shfl_xor(psum, 32);
    l = l * f + psum;

    // pack P(t) -> LDS buf[t&1]
    #pragma unroll
    for (int st = 0; st < 4; ++st) {
      ushort4 w;
      unsigned short* wp = (unsigned short*)&w;
      #pragma unroll
      for (int i = 0; i < 4; ++i) wp[i] = f2bf(p[st][i]);
      *reinterpret_cast<ushort4*>(&P[h][t & 1][lr][st * 16 + lg * 4]) = w;
    }

    // PV(t-1) (m(t-1) domain), then rescale O by f
    if (t > 0) {
      o0 = mfma16(vp[0][0], pf0, o0);
      o0 = mfma16(vp[0][1], pf1, o0);
      o1 = mfma16(vp[1][0], pf0, o1);
      o1 = mfma16(vp[1][1], pf1, o1);
    }
    #pragma unroll
    for (int i = 0; i < 4; ++i) { o0[i] *= f; o1[i] *= f; }

    // V generation swap: vp <- V(t), issue V(t+1)
    #pragma unroll
    for (int dh = 0; dh < 2; ++dh)
      #pragma unroll
      for (int ks = 0; ks < 2; ++ks)
        vp[dh][ks] = vn[dh][ks];
    if (t < 15) {
      #pragma unroll
      for (int dh = 0; dh < 2; ++dh)
        #pragma unroll
        for (int ks = 0; ks < 2; ++ks)
          vn[dh][ks] = ldfrag(Vh + (dh * 16 + lr) * 1024 + k0 + 64 + ks * 32 + lg * 8);
      #pragma unroll
      for (int tt = 0; tt < 4; ++tt)
        bc[tt] = bn[tt];
    }
  }

  // epilogue: PV(15)
  {
    const unsigned short* pb = &P[h][1][lr][0];
    const bf16x8 pf0 = *reinterpret_cast<const bf16x8*>(pb + lg * 8);
    const bf16x8 pf1 = *reinterpret_cast<const bf16x8*>(pb + 32 + lg * 8);
    o0 = mfma16(vp[0][0], pf0, o0);
    o0 = mfma16(vp[0][1], pf1, o0);
    o1 = mfma16(vp[1][0], pf0, o1);
    o1 = mfma16(vp[1][1], pf1, o1);
  }

  const float linv = 1.0f / l;                // per-lane (q = lr)
  ushort4 r0, r1;
  unsigned short* r0p = (unsigned short*)&r0;
  unsigned short* r1p = (unsigned short*)&r1;
  #pragma unroll
  for (int i = 0; i < 4; ++i) {
    r0p[i] = f2bf(o0[i] * linv);
    r1p[i] = f2bf(o1[i] * linv);
  }
  const int row = (b << 10) + q0 + lr;
  *reinterpret_cast<ushort4*>(&AO[row * 256 + h * 32 + lg * 4]) = r0;
  *reinterpret_cast<ushort4*>(&AO[row * 256 + h * 32 + 16 + lg * 4]) = r1;
}

// ---------------- output projection -------------------------------------------
// grid (512, 2): x = m-tile of 16, y = 128-col half.
__global__ __launch_bounds__(256, 2) void k_oproj(
    const unsigned short* __restrict__ AO, const unsigned short* __restrict__ Wto,
    const float* __restrict__ bo, float* __restrict__ out) {
  const int lane = threadIdx.x & 63;
  const int w = threadIdx.x >> 6;
  const int lr = lane & 15, lg = lane >> 4;
  const int m0 = blockIdx.x << 4;

  bf16x8 a[8];
  #pragma unroll
  for (int ks = 0; ks < 8; ++ks)
    a[ks] = ldfrag(AO + (m0 + lr) * 256 + ks * 32 + lg * 8);

  #pragma unroll
  for (int j = 0; j < 2; ++j) {
    const int c0 = (blockIdx.y * 2 + j) * 64 + w * 16;
    bf16x8 bfr[8];
    #pragma unroll
    for (int ks = 0; ks < 8; ++ks)
      bfr[ks] = ldfrag(Wto + (c0 + lr) * 256 + ks * 32 + lg * 8);
    f32x4 acc = {0.f, 0.f, 0.f, 0.f};
    #pragma unroll
    for (int ks = 0; ks < 8; ++ks)
      acc = mfma16(a[ks], bfr[ks], acc);
    const float bb = bo[c0 + lr];
    #pragma unroll
    for (int i = 0; i < 4; ++i) {
      const int row = m0 + lg * 4 + i;
      out[row * 256 + c0 + lr] = acc[i] + bb;
    }
  }
}

extern "C" void kernel_launch(void* const* d_in, const int* in_sizes, int n_in,
                              void* d_out, int out_size, void* d_ws, size_t ws_size,
                              hipStream_t stream) {
  const float* X   = (const float*)d_in[0];
  const int*   A   = (const int*)d_in[1];
  const float* D   = (const float*)d_in[2];
  const float* Wq  = (const float*)d_in[3];
  const float* bq  = (const float*)d_in[4];
  const float* Wk  = (const float*)d_in[5];
  const float* bk  = (const float*)d_in[6];
  const float* Wv  = (const float*)d_in[7];
  const float* bv  = (const float*)d_in[8];
  const float* Wo  = (const float*)d_in[9];
  const float* bo  = (const float*)d_in[10];
  const float* dsc = (const float*)d_in[11];
  float* out = (float*)d_out;

  unsigned short* ws = (unsigned short*)d_ws;
  unsigned short* Xbf  = ws;                   // 2,097,152  (reused as AO later)
  unsigned short* Wt   = ws + 2097152;         //   262,144
  unsigned short* Qb   = ws + 2359296;         // 2,097,152
  unsigned short* Kb   = ws + 4456448;         // 2,097,152
  unsigned short* Vt   = ws + 6553600;         // 2,097,152
  unsigned short* Bias = ws + 8650752;         // 8,388,608  (total ~34.1 MB)
  unsigned short* AO   = Xbf;                  // alias: Xbf dead after k_qkv

  hipLaunchKernelGGL(k_prep, dim3(11264), dim3(256), 0, stream,
                     X, A, D, dsc, Wq, Wk, Wv, Wo, Xbf, Wt, Bias);
  hipLaunchKernelGGL(k_qkv, dim3(512, 3), dim3(256), 0, stream,
                     Xbf, Wt, bq, bk, bv, Qb, Kb, Vt);
  hipLaunchKernelGGL(k_attn, dim3(512), dim3(512), 0, stream,
                     Qb, Kb, Vt, Bias, AO);
  hipLaunchKernelGGL(k_oproj, dim3(512, 2), dim3(256), 0, stream,
                     AO, Wt + 196608, bo, out);
}

// Round 5
// 137.393 us; speedup vs baseline: 1.4788x; 1.0053x over previous
//
#include <hip/hip_runtime.h>

// MultiHeadGraphAttention: B=8, N=1024, IN=OUT=256, H=8, d_k=32
// prep(cvt + fused mask/dist bias fp16) -> QKV gemm (bf16 MFMA, Q pre-scaled)
// -> fused masked attention (S^T/O^T, exp2 domain, FIXED-max softmax: p =
//    exp2(s+bias) unnormalized, per-lane l accumulation, 64-key pipelined
//    iters, XCD-affine blocks, double-buffered P) -> out proj.

typedef __bf16 bf16x8 __attribute__((ext_vector_type(8)));
typedef __bf16 bf16x4 __attribute__((ext_vector_type(4)));
typedef float f32x4 __attribute__((ext_vector_type(4)));
typedef int i32x4 __attribute__((ext_vector_type(4)));

#define DEV static __device__ __forceinline__

#define LOG2E 1.4426950408889634f
#define QSCALE 0.2550351062f   // (1/sqrt(32)) * log2(e)

DEV unsigned short f2bf(float f) {   // RNE f32 -> bf16 bits
  union { float f; unsigned u; } x; x.f = f;
  unsigned r = x.u + 0x7fffu + ((x.u >> 16) & 1u);
  return (unsigned short)(r >> 16);
}

DEV unsigned short f2h(float f) {    // f32 -> fp16 bits (RNE)
  _Float16 h = (_Float16)f;
  unsigned short u;
  __builtin_memcpy(&u, &h, 2);
  return u;
}

DEV float h2f(unsigned short u) {    // fp16 bits -> f32
  _Float16 h;
  __builtin_memcpy(&h, &u, 2);
  return (float)h;
}

DEV f32x4 mfma16(bf16x8 a, bf16x8 b, f32x4 c) {
  return __builtin_amdgcn_mfma_f32_16x16x32_bf16(a, b, c, 0, 0, 0);
}

DEV bf16x8 ldfrag(const unsigned short* p) {
  return *reinterpret_cast<const bf16x8*>(p);
}

// ---------------- prep ---------------------------------------------------------
__global__ __launch_bounds__(256) void k_prep(
    const float* __restrict__ X, const int* __restrict__ A,
    const float* __restrict__ D, const float* __restrict__ dscale,
    const float* __restrict__ Wq, const float* __restrict__ Wk,
    const float* __restrict__ Wv, const float* __restrict__ Wo,
    unsigned short* __restrict__ Xbf, unsigned short* __restrict__ Wt,
    unsigned short* __restrict__ Bias) {
  const int tid = blockIdx.x * 256 + threadIdx.x;
  const int NB4 = (8 * 1024 * 1024) / 4;      // 2,097,152 bias quads
  const int NX4 = (8192 * 256) / 4;           //   524,288 X quads
  if (tid < NB4) {
    const i32x4 a4 = reinterpret_cast<const i32x4*>(A)[tid];
    const f32x4 d4 = reinterpret_cast<const f32x4*>(D)[tid];
    const float c = -dscale[0] * LOG2E;
    ushort4 o;
    unsigned short* op = (unsigned short*)&o;
    #pragma unroll
    for (int i = 0; i < 4; ++i)
      op[i] = f2h(a4[i] <= 0 ? -60000.0f : c * d4[i]);
    reinterpret_cast<ushort4*>(Bias)[tid] = o;
  } else if (tid < NB4 + NX4) {
    const int t = tid - NB4;
    float4 v = reinterpret_cast<const float4*>(X)[t];
    ushort4 o;
    o.x = f2bf(v.x); o.y = f2bf(v.y); o.z = f2bf(v.z); o.w = f2bf(v.w);
    reinterpret_cast<ushort4*>(Xbf)[t] = o;
  } else {
    int t = tid - NB4 - NX4;                  // 0 .. 262143
    int mat = t >> 16;
    int e = t & 65535;
    int n = e >> 8, k = e & 255;              // output Wt[mat][n][k]
    const float* W = (mat == 0) ? Wq : (mat == 1) ? Wk : (mat == 2) ? Wv : Wo;
    Wt[t] = f2bf(W[k * 256 + n]);
  }
}

// ---------------- QKV projection GEMM -----------------------------------------
// grid (512, 3): x = m-tile of 16, y = matrix (0=Q 1=K 2=V). block 256 (4 waves),
// wave w covers 16 cols of each 64-col slab. Q pre-scaled by QSCALE.
__global__ __launch_bounds__(256, 2) void k_qkv(
    const unsigned short* __restrict__ Xbf, const unsigned short* __restrict__ Wt,
    const float* __restrict__ bq, const float* __restrict__ bk,
    const float* __restrict__ bv,
    unsigned short* __restrict__ Qb, unsigned short* __restrict__ Kb,
    unsigned short* __restrict__ Vt) {
  const int lane = threadIdx.x & 63;
  const int w = threadIdx.x >> 6;
  const int lr = lane & 15, lg = lane >> 4;
  const int m0 = blockIdx.x << 4;
  const int mat = blockIdx.y;

  bf16x8 a[8];
  #pragma unroll
  for (int ks = 0; ks < 8; ++ks)
    a[ks] = ldfrag(Xbf + (m0 + lr) * 256 + ks * 32 + lg * 8);

  const unsigned short* Wm = Wt + mat * 65536;
  const float* bias = (mat == 0) ? bq : (mat == 1) ? bk : bv;

  #pragma unroll
  for (int nb = 0; nb < 4; ++nb) {
    const int nloc = nb * 64 + w * 16;
    bf16x8 bfr[8];
    #pragma unroll
    for (int ks = 0; ks < 8; ++ks)
      bfr[ks] = ldfrag(Wm + (nloc + lr) * 256 + ks * 32 + lg * 8);
    f32x4 acc = {0.f, 0.f, 0.f, 0.f};
    #pragma unroll
    for (int ks = 0; ks < 8; ++ks)
      acc = mfma16(a[ks], bfr[ks], acc);
    const float bb = bias[nloc + lr];
    const int cm = nloc + lr;
    const int hh = cm >> 5, d = cm & 31;
    if (mat == 2) {                           // V transposed: 4 consecutive halfs
      ushort4 vv;
      unsigned short* vp = (unsigned short*)&vv;
      #pragma unroll
      for (int i = 0; i < 4; ++i) vp[i] = f2bf(acc[i] + bb);
      const int row = m0 + lg * 4;
      const int bidx = row >> 10, nn = row & 1023;
      *reinterpret_cast<ushort4*>(&Vt[(((bidx * 8 + hh) * 32) + d) * 1024 + nn]) = vv;
    } else if (mat == 0) {
      #pragma unroll
      for (int i = 0; i < 4; ++i) {
        const int row = m0 + lg * 4 + i;
        const int bidx = row >> 10, nn = row & 1023;
        Qb[(((bidx * 8 + hh) * 1024) + nn) * 32 + d] = f2bf((acc[i] + bb) * QSCALE);
      }
    } else {
      #pragma unroll
      for (int i = 0; i < 4; ++i) {
        const int row = m0 + lg * 4 + i;
        const int bidx = row >> 10, nn = row & 1023;
        Kb[(((bidx * 8 + hh) * 1024) + nn) * 32 + d] = f2bf(acc[i] + bb);
      }
    }
  }
}

// ---------------- fused masked attention --------------------------------------
// grid 512: b = blockIdx&7 (XCD-affine), q0 = (blockIdx>>3)*16. 8 waves = heads.
// 64 keys/iter, 16 iters. S^T (q in lanes) + O^T (O cols = q).
// Fixed-max softmax: p = exp2(s + bias) unnormalized (bias <= 0, masked ->
// -60000 -> p = 0 exactly); l accumulated per-lane, reduced once at the end.
// No cross-iteration serial chain -> deep pipelining. P double-buffered in LDS,
// PV lags one iteration so the LDS round-trip overlaps the exp/pack VALU work.
__global__ __launch_bounds__(512, 4) void k_attn(
    const unsigned short* __restrict__ Qb, const unsigned short* __restrict__ Kb,
    const unsigned short* __restrict__ Vt, const unsigned short* __restrict__ Bias,
    unsigned short* __restrict__ AO) {
  __shared__ unsigned short P[8][2][16][72];  // [head][buf][q][64 keys + pad]
  const int lane = threadIdx.x & 63;
  const int h = threadIdx.x >> 6;
  const int lr = lane & 15, lg = lane >> 4;
  const int b = blockIdx.x & 7;               // XCD affinity: batch b -> XCD b
  const int q0 = (blockIdx.x >> 3) << 4;

  const unsigned short* Qh = Qb + (size_t)((b * 8 + h) * 1024) * 32;
  const unsigned short* Kh = Kb + (size_t)((b * 8 + h) * 1024) * 32;
  const unsigned short* Vh = Vt + (size_t)((b * 8 + h) * 32) * 1024;
  const unsigned short* Brow = Bias + ((size_t)b << 20) + (size_t)(q0 + lr) * 1024;

  const bf16x8 qf = ldfrag(Qh + (q0 + lr) * 32 + lg * 8);

  f32x4 o0 = {0.f, 0.f, 0.f, 0.f}, o1 = {0.f, 0.f, 0.f, 0.f};
  float psum = 0.f;

  // prologue: K(0), V(0), bias(0)
  bf16x8 kf[4], vp[2][2], vn[2][2];
  ushort4 bc[4], bn[4];
  #pragma unroll
  for (int s = 0; s < 4; ++s)
    kf[s] = ldfrag(Kh + (s * 16 + lr) * 32 + lg * 8);
  #pragma unroll
  for (int dh = 0; dh < 2; ++dh)
    #pragma unroll
    for (int ks = 0; ks < 2; ++ks)
      vn[dh][ks] = ldfrag(Vh + (dh * 16 + lr) * 1024 + ks * 32 + lg * 8);
  #pragma unroll
  for (int tt = 0; tt < 4; ++tt)
    bc[tt] = *reinterpret_cast<const ushort4*>(Brow + tt * 16 + lg * 4);

  for (int t = 0; t < 16; ++t) {
    const int k0 = t << 6;
    // issue bias(t+1) early (HBM-cold stream)
    if (t < 15) {
      #pragma unroll
      for (int tt = 0; tt < 4; ++tt)
        bn[tt] = *reinterpret_cast<const ushort4*>(Brow + k0 + 64 + tt * 16 + lg * 4);
    }

    // QK^T: s[st] rows = keys k0+st*16+lg*4+i, cols = q (lane lr)
    const f32x4 zz = {0.f, 0.f, 0.f, 0.f};
    f32x4 s[4];
    #pragma unroll
    for (int st = 0; st < 4; ++st)
      s[st] = mfma16(kf[st], qf, zz);

    // issue K(t+1) (kf consumed by the mfmas above)
    if (t < 15) {
      #pragma unroll
      for (int st = 0; st < 4; ++st)
        kf[st] = ldfrag(Kh + (k0 + 64 + st * 16 + lr) * 32 + lg * 8);
    }

    // issue P(t-1) read early; completes under the exp/pack below
    bf16x8 pf0, pf1;
    if (t > 0) {
      const unsigned short* pb = &P[h][(t - 1) & 1][lr][0];
      pf0 = *reinterpret_cast<const bf16x8*>(pb + lg * 8);
      pf1 = *reinterpret_cast<const bf16x8*>(pb + 32 + lg * 8);
    }

    // p = exp2(s + bias), unnormalized (fixed max 0); accumulate l per-lane
    float p[4][4];
    #pragma unroll
    for (int st = 0; st < 4; ++st) {
      const unsigned short* bp = (const unsigned short*)&bc[st];
      #pragma unroll
      for (int i = 0; i < 4; ++i) {
        p[st][i] = exp2f(s[st][i] + h2f(bp[i]));
        psum += p[st][i];
      }
    }

    // pack P(t) -> LDS buf[t&1] (v_cvt_pk_bf16_f32 pairs)
    #pragma unroll
    for (int st = 0; st < 4; ++st) {
      bf16x4 w;
      #pragma unroll
      for (int i = 0; i < 4; ++i) w[i] = (__bf16)p[st][i];
      *reinterpret_cast<bf16x4*>(&P[h][t & 1][lr][st * 16 + lg * 4]) = w;
    }

    // PV(t-1)
    if (t > 0) {
      o0 = mfma16(vp[0][0], pf0, o0);
      o0 = mfma16(vp[0][1], pf1, o0);
      o1 = mfma16(vp[1][0], pf0, o1);
      o1 = mfma16(vp[1][1], pf1, o1);
    }

    // V generation swap: vp <- V(t), issue V(t+1)
    #pragma unroll
    for (int dh = 0; dh < 2; ++dh)
      #pragma unroll
      for (int ks = 0; ks < 2; ++ks)
        vp[dh][ks] = vn[dh][ks];
    if (t < 15) {
      #pragma unroll
      for (int dh = 0; dh < 2; ++dh)
        #pragma unroll
        for (int ks = 0; ks < 2; ++ks)
          vn[dh][ks] = ldfrag(Vh + (dh * 16 + lr) * 1024 + k0 + 64 + ks * 32 + lg * 8);
      #pragma unroll
      for (int tt = 0; tt < 4; ++tt)
        bc[tt] = bn[tt];
    }
  }

  // epilogue: PV(15)
  {
    const unsigned short* pb = &P[h][1][lr][0];
    const bf16x8 pf0 = *reinterpret_cast<const bf16x8*>(pb + lg * 8);
    const bf16x8 pf1 = *reinterpret_cast<const bf16x8*>(pb + 32 + lg * 8);
    o0 = mfma16(vp[0][0], pf0, o0);
    o0 = mfma16(vp[0][1], pf1, o0);
    o1 = mfma16(vp[1][0], pf0, o1);
    o1 = mfma16(vp[1][1], pf1, o1);
  }

  // l reduction: once, at the end (q = lr class: lanes lr, lr+16, lr+32, lr+48)
  psum += __shfl_xor(psum, 16);
  psum += __shfl_xor(psum, 32);
  const float linv = 1.0f / psum;             // per-lane (q = lr)

  ushort4 r0, r1;
  unsigned short* r0p = (unsigned short*)&r0;
  unsigned short* r1p = (unsigned short*)&r1;
  #pragma unroll
  for (int i = 0; i < 4; ++i) {
    r0p[i] = f2bf(o0[i] * linv);
    r1p[i] = f2bf(o1[i] * linv);
  }
  const int row = (b << 10) + q0 + lr;
  *reinterpret_cast<ushort4*>(&AO[row * 256 + h * 32 + lg * 4]) = r0;
  *reinterpret_cast<ushort4*>(&AO[row * 256 + h * 32 + 16 + lg * 4]) = r1;
}

// ---------------- output projection -------------------------------------------
// grid (512, 2): x = m-tile of 16, y = 128-col half.
__global__ __launch_bounds__(256, 2) void k_oproj(
    const unsigned short* __restrict__ AO, const unsigned short* __restrict__ Wto,
    const float* __restrict__ bo, float* __restrict__ out) {
  const int lane = threadIdx.x & 63;
  const int w = threadIdx.x >> 6;
  const int lr = lane & 15, lg = lane >> 4;
  const int m0 = blockIdx.x << 4;

  bf16x8 a[8];
  #pragma unroll
  for (int ks = 0; ks < 8; ++ks)
    a[ks] = ldfrag(AO + (m0 + lr) * 256 + ks * 32 + lg * 8);

  #pragma unroll
  for (int j = 0; j < 2; ++j) {
    const int c0 = (blockIdx.y * 2 + j) * 64 + w * 16;
    bf16x8 bfr[8];
    #pragma unroll
    for (int ks = 0; ks < 8; ++ks)
      bfr[ks] = ldfrag(Wto + (c0 + lr) * 256 + ks * 32 + lg * 8);
    f32x4 acc = {0.f, 0.f, 0.f, 0.f};
    #pragma unroll
    for (int ks = 0; ks < 8; ++ks)
      acc = mfma16(a[ks], bfr[ks], acc);
    const float bb = bo[c0 + lr];
    #pragma unroll
    for (int i = 0; i < 4; ++i) {
      const int row = m0 + lg * 4 + i;
      out[row * 256 + c0 + lr] = acc[i] + bb;
    }
  }
}

extern "C" void kernel_launch(void* const* d_in, const int* in_sizes, int n_in,
                              void* d_out, int out_size, void* d_ws, size_t ws_size,
                              hipStream_t stream) {
  const float* X   = (const float*)d_in[0];
  const int*   A   = (const int*)d_in[1];
  const float* D   = (const float*)d_in[2];
  const float* Wq  = (const float*)d_in[3];
  const float* bq  = (const float*)d_in[4];
  const float* Wk  = (const float*)d_in[5];
  const float* bk  = (const float*)d_in[6];
  const float* Wv  = (const float*)d_in[7];
  const float* bv  = (const float*)d_in[8];
  const float* Wo  = (const float*)d_in[9];
  const float* bo  = (const float*)d_in[10];
  const float* dsc = (const float*)d_in[11];
  float* out = (float*)d_out;

  unsigned short* ws = (unsigned short*)d_ws;
  unsigned short* Xbf  = ws;                   // 2,097,152  (reused as AO later)
  unsigned short* Wt   = ws + 2097152;         //   262,144
  unsigned short* Qb   = ws + 2359296;         // 2,097,152
  unsigned short* Kb   = ws + 4456448;         // 2,097,152
  unsigned short* Vt   = ws + 6553600;         // 2,097,152
  unsigned short* Bias = ws + 8650752;         // 8,388,608  (total ~34.1 MB)
  unsigned short* AO   = Xbf;                  // alias: Xbf dead after k_qkv

  hipLaunchKernelGGL(k_prep, dim3(11264), dim3(256), 0, stream,
                     X, A, D, dsc, Wq, Wk, Wv, Wo, Xbf, Wt, Bias);
  hipLaunchKernelGGL(k_qkv, dim3(512, 3), dim3(256), 0, stream,
                     Xbf, Wt, bq, bk, bv, Qb, Kb, Vt);
  hipLaunchKernelGGL(k_attn, dim3(512), dim3(512), 0, stream,
                     Qb, Kb, Vt, Bias, AO);
  hipLaunchKernelGGL(k_oproj, dim3(512, 2), dim3(256), 0, stream,
                     AO, Wt + 196608, bo, out);
}